// Round 19
// baseline (1020.750 us; speedup 1.0000x reference)
//
#include <hip/hip_runtime.h>
#include <hip/hip_bf16.h>
#include <math.h>

// Problem constants
#define NN 8
#define CH 256
#define HH 64
#define WW 64
#define AA 27
#define KK 100
#define MM (HH * WW * AA)   // 110592 per image

typedef __attribute__((ext_vector_type(8))) short short8v;
typedef __attribute__((ext_vector_type(4))) float float4v;

#define SPL 8921088ull    // elems per padded NHWC split plane: 8*66*66*256
#define WSPL 589824ull     // elems per weight split plane: 9*256*256

// LDS partition (bytes): A dbuf only (B_h now lives in registers).
#define ABUF_B 25344
#define LDS_TOTAL (2 * ABUF_B)   // 50688

// ---------------------------------------------------------------------------
// split fp32 -> 3-way bf16 (h + m + l reconstructs to ~2^-24 rel)
// ---------------------------------------------------------------------------
__device__ inline void split3(float x, __hip_bfloat16& h, __hip_bfloat16& m,
                              __hip_bfloat16& l)
{
    h = __float2bfloat16(x);
    float r = x - __bfloat162float(h);
    m = __float2bfloat16(r);
    float r2 = r - __bfloat162float(m);
    l = __float2bfloat16(r2);
}

// ---------------------------------------------------------------------------
// Combined misc prep: [0,1560) zero halo borders; [1560,1816) w1 split;
// [1816,2072) w2 split. One launch instead of three.
// ---------------------------------------------------------------------------
__global__ __launch_bounds__(256)
void prep_misc(__hip_bfloat16* a3, __hip_bfloat16* f1,
               const float* __restrict__ w1, __hip_bfloat16* __restrict__ wt1,
               const float* __restrict__ w2, __hip_bfloat16* __restrict__ wt2)
{
    const int bid = blockIdx.x;
    const int tid = threadIdx.x;
    if (bid < 1560) {
        int g = bid * 256 + tid;       // exactly 399360
        int arr = g / 66560;
        int rem = g - arr * 66560;
        int n = rem / 8320;
        int rem2 = rem - n * 8320;
        int b = rem2 >> 5;
        int q = rem2 & 31;
        int hp, wp;
        if (b < 66)       { hp = 0;        wp = b; }
        else if (b < 132) { hp = 65;       wp = b - 66; }
        else if (b < 196) { hp = b - 131;  wp = 0; }
        else              { hp = b - 195;  wp = 65; }
        __hip_bfloat16* base = (arr < 3) ? (a3 + (size_t)arr * SPL)
                                         : (f1 + (size_t)(arr - 3) * SPL);
        short8v z = {0, 0, 0, 0, 0, 0, 0, 0};
        *(short8v*)(base + (((size_t)n * 66 + hp) * 66 + wp) * 256 + q * 8) = z;
    } else {
        const bool second = (bid >= 1816);
        const float* w = second ? w2 : w1;
        __hip_bfloat16* wT = second ? wt2 : wt1;
        int t = (bid - (second ? 1816 : 1560)) * 256 + tid;   // 65536
        int co = t >> 8, ci = t & 255;
        const float* src = w + (size_t)t * 9;
#pragma unroll
        for (int tap = 0; tap < 9; ++tap) {
            __hip_bfloat16 h, m, l;
            split3(src[tap], h, m, l);
            size_t base = ((size_t)tap * 256 + co) * 256 + ci;
            wT[base] = h;
            wT[base + WSPL] = m;
            wT[base + 2 * WSPL] = l;
        }
    }
}

// ---------------------------------------------------------------------------
// p4 NCHW fp32 -> padded NHWC bf16 x3 splits.
// ---------------------------------------------------------------------------
__global__ __launch_bounds__(256)
void prep_in(const float* __restrict__ in, __hip_bfloat16* __restrict__ a3)
{
    __shared__ float s_t[64][65];
    const int tid = threadIdx.x;
    const int ct = blockIdx.x & 3;
    const int row = (blockIdx.x >> 2) & 63;
    const int n = blockIdx.x >> 8;
    const int ci0 = ct * 64;

    for (int i = tid; i < 64 * 64; i += 256) {
        int ci = i >> 6, px = i & 63;
        s_t[ci][px] = in[((size_t)(n * 256 + ci0 + ci) << 12) + (row << 6) + px];
    }
    __syncthreads();
    for (int i = tid; i < 64 * 64; i += 256) {
        int px = i >> 6, ci = i & 63;
        __hip_bfloat16 h, m, l;
        split3(s_t[ci][px], h, m, l);
        size_t base = (((size_t)n * 66 + row + 1) * 66 + px + 1) * 256 + ci0 + ci;
        a3[base] = h;
        a3[base + SPL] = m;
        a3[base + 2 * SPL] = l;
    }
}

// ---------------------------------------------------------------------------
// MFMA 3x3 conv — r14/r18 numerics (bitwise: same operand bytes, same
// per-acc MFMA order (chunk, as, tap, bs) -> absmax 0.125) with one
// scheduling/layout change: B_h REGISTERS instead of LDS.
// B_h fragments are IDENTICAL across a chunk's 3 as-phases; r18 re-read them
// from LDS every phase (LDS-read was the critical path: 4600cyc/phase vs
// 4150/2765/1382 MFMA). Now: loaded from global (L2-hot) into 144 VGPRs once
// per chunk, reused by all 3 phases. Removes STAGE_B + BBUF + 14 barriers;
// per-phase LDS reads halve. Values identical (direct global read == the
// involution-swizzled LDS round-trip bytes).
// Geometry: co-tile 128, 512 thr (8 waves), grid 256 (1 block/CU),
// A dbuf via global_load_lds with T2 swizzle both-sides (r13/r14 verified),
// B m/l from global inline (unchanged).
// ---------------------------------------------------------------------------
typedef __attribute__((address_space(3))) unsigned lds_u32;
typedef const __attribute__((address_space(1))) unsigned glb_u32;

#define AB_PTR(I_)  ((__hip_bfloat16*)(smem + (I_) * ABUF_B))

#define STAGE_A(AS_, CI0_, DST_)  do {                                         \
    const __hip_bfloat16* src_ = a3 + (size_t)(AS_) * SPL +                    \
        ((size_t)(n * 66 + rt * 4) * 66) * 256 + (CI0_);                       \
    __hip_bfloat16* dst_ = (DST_);                                             \
    _Pragma("unroll")                                                          \
    for (int it = 0; it < 4; ++it) {                                           \
        int c = it * 512 + tid;                                                \
        if (c < 1584) {                                                        \
            int ph_ = c >> 3;                                                  \
            int x_ = ph_ & 7;                                                  \
            int p_ = ph_ * 2 + (((c >> 2) ^ (x_ >> 2)) & 1);                   \
            int q_ = (c & 3) ^ (x_ & 3);                                       \
            __builtin_amdgcn_global_load_lds(                                  \
                (glb_u32*)(src_ + (size_t)p_ * 256 + q_ * 8),                  \
                (lds_u32*)(dst_ + c * 8), 16, 0, 0);                           \
        }                                                                      \
    }                                                                          \
} while (0)

#define CONV_COMPUTE(NB_, SB_)  do {                                           \
    const __hip_bfloat16* sb_ = (SB_);                                         \
    _Pragma("unroll")                                                          \
    for (int tap = 0; tap < 9; ++tap) {                                        \
        const int dy_ = tap / 3, dx_ = tap % 3;                                \
        const int pA_ = ((w & 3) + dy_) * 66 + dx_ + l15;                      \
        const int aoff_ = ((((pA_ << 2) | l4) ^ ((pA_ >> 1) & 7)) << 3);       \
        short8v af0 = *(const short8v*)(sb_ + aoff_);                          \
        short8v af1 = *(const short8v*)(sb_ + aoff_ + 512);                    \
        short8v af2 = *(const short8v*)(sb_ + aoff_ + 1024);                   \
        short8v af3 = *(const short8v*)(sb_ + aoff_ + 1536);                   \
        /* bs = 0: B h-split from REGISTERS (loaded once per chunk) */         \
        {                                                                      \
            short8v b0_ = bh[tap][0];                                          \
            short8v b1_ = bh[tap][1];                                          \
            short8v b2_ = bh[tap][2];                                          \
            short8v b3_ = bh[tap][3];                                          \
            acc[0][0] = __builtin_amdgcn_mfma_f32_16x16x32_bf16(af0, b0_, acc[0][0], 0, 0, 0); \
            acc[1][0] = __builtin_amdgcn_mfma_f32_16x16x32_bf16(af1, b0_, acc[1][0], 0, 0, 0); \
            acc[2][0] = __builtin_amdgcn_mfma_f32_16x16x32_bf16(af2, b0_, acc[2][0], 0, 0, 0); \
            acc[3][0] = __builtin_amdgcn_mfma_f32_16x16x32_bf16(af3, b0_, acc[3][0], 0, 0, 0); \
            acc[0][1] = __builtin_amdgcn_mfma_f32_16x16x32_bf16(af0, b1_, acc[0][1], 0, 0, 0); \
            acc[1][1] = __builtin_amdgcn_mfma_f32_16x16x32_bf16(af1, b1_, acc[1][1], 0, 0, 0); \
            acc[2][1] = __builtin_amdgcn_mfma_f32_16x16x32_bf16(af2, b1_, acc[2][1], 0, 0, 0); \
            acc[3][1] = __builtin_amdgcn_mfma_f32_16x16x32_bf16(af3, b1_, acc[3][1], 0, 0, 0); \
            acc[0][2] = __builtin_amdgcn_mfma_f32_16x16x32_bf16(af0, b2_, acc[0][2], 0, 0, 0); \
            acc[1][2] = __builtin_amdgcn_mfma_f32_16x16x32_bf16(af1, b2_, acc[1][2], 0, 0, 0); \
            acc[2][2] = __builtin_amdgcn_mfma_f32_16x16x32_bf16(af2, b2_, acc[2][2], 0, 0, 0); \
            acc[3][2] = __builtin_amdgcn_mfma_f32_16x16x32_bf16(af3, b2_, acc[3][2], 0, 0, 0); \
            acc[0][3] = __builtin_amdgcn_mfma_f32_16x16x32_bf16(af0, b3_, acc[0][3], 0, 0, 0); \
            acc[1][3] = __builtin_amdgcn_mfma_f32_16x16x32_bf16(af1, b3_, acc[1][3], 0, 0, 0); \
            acc[2][3] = __builtin_amdgcn_mfma_f32_16x16x32_bf16(af2, b3_, acc[2][3], 0, 0, 0); \
            acc[3][3] = __builtin_amdgcn_mfma_f32_16x16x32_bf16(af3, b3_, acc[3][3], 0, 0, 0); \
        }                                                                      \
        /* bs = 1..NB-1: B m/l splits from global */                           \
        const __hip_bfloat16* wp_ = wbase + (size_t)(tap * 65536 + ci0);       \
        _Pragma("unroll")                                                      \
        for (int bs = 1; bs < (NB_); ++bs) {                                   \
            const __hip_bfloat16* wq_ = wp_ + (size_t)bs * WSPL;               \
            short8v b0_ = *(const short8v*)(wq_);                              \
            short8v b1_ = *(const short8v*)(wq_ + 4096);                       \
            short8v b2_ = *(const short8v*)(wq_ + 8192);                       \
            short8v b3_ = *(const short8v*)(wq_ + 12288);                      \
            acc[0][0] = __builtin_amdgcn_mfma_f32_16x16x32_bf16(af0, b0_, acc[0][0], 0, 0, 0); \
            acc[1][0] = __builtin_amdgcn_mfma_f32_16x16x32_bf16(af1, b0_, acc[1][0], 0, 0, 0); \
            acc[2][0] = __builtin_amdgcn_mfma_f32_16x16x32_bf16(af2, b0_, acc[2][0], 0, 0, 0); \
            acc[3][0] = __builtin_amdgcn_mfma_f32_16x16x32_bf16(af3, b0_, acc[3][0], 0, 0, 0); \
            acc[0][1] = __builtin_amdgcn_mfma_f32_16x16x32_bf16(af0, b1_, acc[0][1], 0, 0, 0); \
            acc[1][1] = __builtin_amdgcn_mfma_f32_16x16x32_bf16(af1, b1_, acc[1][1], 0, 0, 0); \
            acc[2][1] = __builtin_amdgcn_mfma_f32_16x16x32_bf16(af2, b1_, acc[2][1], 0, 0, 0); \
            acc[3][1] = __builtin_amdgcn_mfma_f32_16x16x32_bf16(af3, b1_, acc[3][1], 0, 0, 0); \
            acc[0][2] = __builtin_amdgcn_mfma_f32_16x16x32_bf16(af0, b2_, acc[0][2], 0, 0, 0); \
            acc[1][2] = __builtin_amdgcn_mfma_f32_16x16x32_bf16(af1, b2_, acc[1][2], 0, 0, 0); \
            acc[2][2] = __builtin_amdgcn_mfma_f32_16x16x32_bf16(af2, b2_, acc[2][2], 0, 0, 0); \
            acc[3][2] = __builtin_amdgcn_mfma_f32_16x16x32_bf16(af3, b2_, acc[3][2], 0, 0, 0); \
            acc[0][3] = __builtin_amdgcn_mfma_f32_16x16x32_bf16(af0, b3_, acc[0][3], 0, 0, 0); \
            acc[1][3] = __builtin_amdgcn_mfma_f32_16x16x32_bf16(af1, b3_, acc[1][3], 0, 0, 0); \
            acc[2][3] = __builtin_amdgcn_mfma_f32_16x16x32_bf16(af2, b3_, acc[2][3], 0, 0, 0); \
            acc[3][3] = __builtin_amdgcn_mfma_f32_16x16x32_bf16(af3, b3_, acc[3][3], 0, 0, 0); \
        }                                                                      \
    }                                                                          \
} while (0)

template <int MODE>
__global__ __launch_bounds__(512, 1)
void conv_mfma(const __hip_bfloat16* __restrict__ a3,
               const __hip_bfloat16* __restrict__ wT,
               const float* __restrict__ bias,
               __hip_bfloat16* __restrict__ outb,
               float* __restrict__ outf)
{
    extern __shared__ __align__(16) char smem[];

    const int tid = threadIdx.x;
    const int lane = tid & 63, w = tid >> 6;      // (w&3)=row, (w>>2)=cohalf
    const int l15 = lane & 15, l4 = lane >> 4;
    const int cohalf = w >> 2;
    const int bid = blockIdx.x;                   // natural order
    const int cg = bid & 1, rt = (bid >> 1) & 15, n = bid >> 5;
    const int co0 = cg * 128;
    const int row = rt * 4 + (w & 3);             // output row 0..63

    float4v acc[4][4];                            // [pixel-tile p][cout-tile q]
#pragma unroll
    for (int p = 0; p < 4; ++p)
#pragma unroll
        for (int q = 0; q < 4; ++q) acc[p][q] = (float4v){0.f, 0.f, 0.f, 0.f};

    // B base: [split][tap][co][ci]
    const __hip_bfloat16* wbase = wT + ((size_t)(co0 + cohalf * 64 + l15)) * 256 + l4 * 8;

    // -------- pipeline: 24 A-phases (chunk, as); B_h in regs per chunk ----
    STAGE_A(0, 0, AB_PTR(0));
    __syncthreads();

    int cur = 0;
    for (int chunk = 0; chunk < 8; ++chunk) {
        const int ci0 = chunk * 32;

        // B_h (split 0) for this chunk -> registers (issued with clean FIFO,
        // before the A prefetches; L2-hot; reused by all 3 phases below).
        short8v bh[9][4];
#pragma unroll
        for (int tap = 0; tap < 9; ++tap) {
            const __hip_bfloat16* wp_ = wbase + (size_t)(tap * 65536 + ci0);
            bh[tap][0] = *(const short8v*)(wp_);
            bh[tap][1] = *(const short8v*)(wp_ + 4096);
            bh[tap][2] = *(const short8v*)(wp_ + 8192);
            bh[tap][3] = *(const short8v*)(wp_ + 12288);
        }

        // as = 0 (NB=3): prefetch A(as=1)
        STAGE_A(1, ci0, AB_PTR(cur ^ 1));
        CONV_COMPUTE(3, AB_PTR(cur));
        __syncthreads();
        cur ^= 1;
        // as = 1 (NB=2): prefetch A(as=2)
        STAGE_A(2, ci0, AB_PTR(cur ^ 1));
        CONV_COMPUTE(2, AB_PTR(cur));
        __syncthreads();
        cur ^= 1;
        // as = 2 (NB=1): prefetch A(as=0, next chunk)
        if (chunk < 7) STAGE_A(0, ci0 + 32, AB_PTR(cur ^ 1));
        CONV_COMPUTE(1, AB_PTR(cur));
        __syncthreads();
        cur ^= 1;
    }

    // epilogue: bias + relu
    float bco[4];
#pragma unroll
    for (int q = 0; q < 4; ++q) bco[q] = bias[co0 + cohalf * 64 + q * 16 + l15];

    if (MODE == 0) {
#pragma unroll
        for (int p = 0; p < 4; ++p)
#pragma unroll
            for (int q = 0; q < 4; ++q) {
#pragma unroll
                for (int v = 0; v < 4; ++v) {
                    float y = fmaxf(acc[p][q][v] + bco[q], 0.f);
                    __hip_bfloat16 h, m, l;
                    split3(y, h, m, l);
                    size_t base = (((size_t)n * 66 + row + 1) * 66 +
                                   p * 16 + l4 * 4 + v + 1) * 256 +
                                  co0 + cohalf * 64 + q * 16 + l15;
                    outb[base] = h;
                    outb[base + SPL] = m;
                    outb[base + 2 * SPL] = l;
                }
            }
    } else {
#pragma unroll
        for (int p = 0; p < 4; ++p)
#pragma unroll
            for (int q = 0; q < 4; ++q) {
                float4v y;
#pragma unroll
                for (int v = 0; v < 4; ++v) y[v] = fmaxf(acc[p][q][v] + bco[q], 0.f);
                *(float4v*)(outf + ((size_t)(n * 256 + co0 + cohalf * 64 + q * 16 + l15) << 12) +
                            row * 64 + p * 16 + l4 * 4) = y;
            }
    }
}

// ---------------------------------------------------------------------------
// Fused 1x1 convs: 135 output channels (27 logits + 108 deltas). fp32.
// ---------------------------------------------------------------------------
__global__ __launch_bounds__(256, 2)
void conv1x1_kernel(const float* __restrict__ feat, const float* __restrict__ wc,
                    const float* __restrict__ bc, const float* __restrict__ wb,
                    const float* __restrict__ bb, float* __restrict__ tmp)
{
    __shared__ float s_f[64][64];
    __shared__ float s_w[64][137];

    const int tid  = threadIdx.x;
    const int n    = blockIdx.x >> 6;
    const int px0  = (blockIdx.x & 63) << 6;
    const int lane = tid & 63;
    const int g    = tid >> 6;

    float acc[34];
#pragma unroll
    for (int k = 0; k < 34; ++k) acc[k] = 0.f;

    for (int chb = 0; chb < 4; ++chb) {
        const int ci0 = chb << 6;
        __syncthreads();
        for (int i = tid; i < 64 * 64; i += 256) {
            int ci = i >> 6, pp = i & 63;
            s_f[ci][pp] = feat[(((size_t)n * CH + ci0 + ci) << 12) + px0 + pp];
        }
        for (int i = tid; i < 135 * 64; i += 256) {
            int co = i >> 6, ci = i & 63;
            float wv = (co < 27) ? wc[(size_t)co * CH + ci0 + ci]
                                 : wb[(size_t)(co - 27) * CH + ci0 + ci];
            s_w[ci][co] = wv;
        }
        __syncthreads();
        for (int ci = 0; ci < 64; ++ci) {
            float f = s_f[ci][lane];
#pragma unroll
            for (int k = 0; k < 34; ++k) {
                int co = g * 34 + k;
                acc[k] += f * s_w[ci][co < 135 ? co : 134];
            }
        }
    }
#pragma unroll
    for (int k = 0; k < 34; ++k) {
        int co = g * 34 + k;
        if (co < 135) {
            float b = (co < 27) ? bc[co] : bb[co - 27];
            tmp[((size_t)n * 135 + co) * 4096 + px0 + lane] = acc[k] + b;
        }
    }
}

// ---------------------------------------------------------------------------
// Anchors + apply_deltas + validity + score masking. (unchanged, verified)
// ---------------------------------------------------------------------------
__global__ void boxes_kernel(const float* __restrict__ tmp,
                             float* __restrict__ scores, float* __restrict__ boxes)
{
    const int n = blockIdx.y;
    const int i = blockIdx.x * 256 + threadIdx.x;
    const int a = i >> 12;
    const int p = i & 4095;

    const float* t = tmp + (size_t)n * 135 * 4096;
    float logit = t[(size_t)a * 4096 + p];
    float d0 = t[((size_t)(27 + a * 4 + 0)) * 4096 + p];
    float d1 = t[((size_t)(27 + a * 4 + 1)) * 4096 + p];
    float d2 = t[((size_t)(27 + a * 4 + 2)) * 4096 + p];
    float d3 = t[((size_t)(27 + a * 4 + 3)) * 4096 + p];

    const int hh = p >> 6, ww = p & 63;
    const int si = a / 9, ri = (a / 3) % 3, sci = a % 3;

    double s  = (si == 0) ? 32.0 : (si == 1 ? 64.0 : 128.0);
    double r  = (ri == 0) ? 0.5 : (ri == 1 ? 1.0 : 2.0);
    double sv = (sci == 0) ? 1.0 : (sci == 1 ? pow(2.0, 1.0 / 3.0) : pow(2.0, 2.0 / 3.0));
    double sq = sqrt(r);
    float wa = (float)fmax(s * sv * sq, 1.0);
    float ha = (float)fmax(s * sv / sq, 1.0);
    float bx1 = -0.5f * wa, by1 = -0.5f * ha, bx2 = 0.5f * wa, by2 = 0.5f * ha;

    float sx = ((float)ww + 0.5f) * 4.0f;
    float sy = ((float)hh + 0.5f) * 4.0f;
    float ax1 = fmaxf(bx1 + sx, 0.f);
    float ay1 = fmaxf(by1 + sy, 0.f);
    float ax2 = fminf(fmaxf(bx2 + sx, 0.f), 256.f);
    float ay2 = fminf(fmaxf(by2 + sy, 0.f), 256.f);

    float wdt = ax2 - ax1, hgt = ay2 - ay1;
    float cx = ax1 + 0.5f * wdt, cy = ay1 + 0.5f * hgt;
    float dx = d0 / 10.f, dy = d1 / 10.f, dw = d2 / 5.f, dh = d3 / 5.f;
    float pcx = dx * wdt + cx, pcy = dy * hgt + cy;
    float pw = fmaxf(expf(dw) * wdt, 1.f);
    float ph = fmaxf(expf(dh) * hgt, 1.f);
    float x1 = fminf(fmaxf(pcx - 0.5f * pw, 0.f), 256.f);
    float y1 = fminf(fmaxf(pcy - 0.5f * ph, 0.f), 256.f);
    float x2 = fminf(fmaxf(pcx + 0.5f * pw, 0.f), 256.f);
    float y2 = fminf(fmaxf(pcy + 0.5f * ph, 0.f), 256.f);

    bool inval = ((x2 - x1) < 1.f) || ((y2 - y1) < 1.f);
    float fx1 = inval ? ax1 : x1, fy1 = inval ? ay1 : y1;
    float fx2 = inval ? ax2 : x2, fy2 = inval ? ay2 : y2;
    bool valid = (fx2 > fx1 + 1.f) && (fy2 > fy1 + 1.f);

    const int m = p * 27 + a;
    scores[(size_t)n * MM + m] = valid ? logit : -INFINITY;
    float4 bx = make_float4(fx1, fy1, fx2, fy2);
    *(float4*)&boxes[((size_t)n * MM + m) * 4] = bx;
}

// ---------------------------------------------------------------------------
// Exact per-image top-100 + gather. Algorithm unchanged; bulk scans (4 radix
// passes + phase A) vectorized to float4 reads (MM % 4096 == 0).
// ---------------------------------------------------------------------------
__device__ inline unsigned ordf(float f)
{
    unsigned u = __float_as_uint(f);
    return (u & 0x80000000u) ? ~u : (u | 0x80000000u);
}

__global__ void topk_props(const float* __restrict__ scores,
                           const float* __restrict__ boxes,
                           float* __restrict__ props)
{
    const int n = blockIdx.x;
    const int tid = threadIdx.x;
    const float* sc = scores + (size_t)n * MM;

    __shared__ unsigned hist[256];
    __shared__ unsigned u_prefix, u_need, cnt;
    __shared__ unsigned long long selk[100];
    __shared__ unsigned wave_tot[16];

    if (tid == 0) { u_prefix = 0; u_need = 100; cnt = 0; }
    __syncthreads();

    for (int pass = 0; pass < 4; ++pass) {
        if (tid < 256) hist[tid] = 0;
        __syncthreads();
        unsigned pf = u_prefix;
        int shift = 24 - pass * 8;
        for (int i4 = tid; i4 < MM / 4; i4 += 1024) {
            float4 v = ((const float4*)sc)[i4];
#pragma unroll
            for (int k = 0; k < 4; ++k) {
                float f = (k == 0) ? v.x : (k == 1) ? v.y : (k == 2) ? v.z : v.w;
                unsigned o = ordf(f);
                bool match = (pass == 0) || ((o >> (shift + 8)) == (pf >> (shift + 8)));
                if (match) atomicAdd(&hist[(o >> shift) & 255u], 1u);
            }
        }
        __syncthreads();
        if (tid == 0) {
            unsigned nd = u_need;
            int b = 255;
            for (;;) {
                unsigned cb = hist[b];
                if (nd <= cb || b == 0) break;
                nd -= cb;
                --b;
            }
            u_need = nd;
            u_prefix = pf | ((unsigned)b << shift);
        }
        __syncthreads();
    }
    const unsigned T = u_prefix;
    const int need = (int)u_need;
    const int cgt = 100 - need;

    // phase A: collect all keys strictly greater than T (exactly cgt)
    for (int i4 = tid; i4 < MM / 4; i4 += 1024) {
        float4 v = ((const float4*)sc)[i4];
#pragma unroll
        for (int k = 0; k < 4; ++k) {
            float f = (k == 0) ? v.x : (k == 1) ? v.y : (k == 2) ? v.z : v.w;
            unsigned o = ordf(f);
            if (o > T) {
                unsigned pz = atomicAdd(&cnt, 1u);
                selk[pz] = ((unsigned long long)o << 32) |
                           (unsigned long long)(~(unsigned)(i4 * 4 + k));
            }
        }
    }
    __syncthreads();

    // phase B: collect `need` lowest-index entries equal to T, in index order
    unsigned hv = 0;
    for (int base = 0; base < MM; base += 1024) {
        int i = base + tid;
        unsigned o = ordf(sc[i]);
        bool f = (o == T);
        unsigned long long bal = __ballot(f);
        if ((tid & 63) == 0) wave_tot[tid >> 6] = (unsigned)__popcll(bal);
        __syncthreads();
        unsigned wbase = 0, tot = 0;
        int wv = tid >> 6;
        for (int w2 = 0; w2 < 16; ++w2) {
            unsigned cw = wave_tot[w2];
            tot += cw;
            if (w2 < wv) wbase += cw;
        }
        if (f) {
            unsigned rk = hv + wbase +
                          (unsigned)__popcll(bal & ((1ull << (tid & 63)) - 1ull));
            if (rk < (unsigned)need)
                selk[cgt + rk] =
                    ((unsigned long long)o << 32) | (unsigned long long)(~(unsigned)i);
        }
        hv += tot;
        __syncthreads();
        if (hv >= (unsigned)need) break;
    }
    __syncthreads();

    if (tid < 100) {
        unsigned long long k = selk[tid];
        int rank = 0;
        for (int j = 0; j < 100; ++j) rank += (selk[j] > k) ? 1 : 0;
        unsigned idx = ~(unsigned)(k & 0xFFFFFFFFull);
        const float* bx = boxes + ((size_t)n * MM + idx) * 4;
        float x1 = bx[0], y1 = bx[1], x2 = bx[2], y2 = bx[3];
        bool v = (x2 > x1 + 1.f) && (y2 > y1 + 1.f);
        float* o = props + ((size_t)n * 100 + rank) * 5;
        o[0] = v ? (float)n : 0.f;
        o[1] = v ? x1 : 0.f;
        o[2] = v ? y1 : 0.f;
        o[3] = v ? x2 : 0.f;
        o[4] = v ? y2 : 0.f;
    }
}

// ---------------------------------------------------------------------------
extern "C" void kernel_launch(void* const* d_in, const int* in_sizes, int n_in,
                              void* d_out, int out_size, void* d_ws, size_t ws_size,
                              hipStream_t stream)
{
    const float* p4 = (const float*)d_in[0];
    const float* w1 = (const float*)d_in[1];
    const float* b1 = (const float*)d_in[2];
    const float* w2 = (const float*)d_in[3];
    const float* b2 = (const float*)d_in[4];
    const float* wc = (const float*)d_in[5];
    const float* bc = (const float*)d_in[6];
    const float* wb = (const float*)d_in[7];
    const float* bb = (const float*)d_in[8];

    float* out   = (float*)d_out;
    float* props = out;            // [8,100,5]
    float* feat  = out + 4000;     // [8,256,64,64] NCHW fp32

    char* ws = (char*)d_ws;
    // layout (bytes):
    //   a3  [0, 53,526,528)             3x bf16 padded-NHWC input splits
    //   f1  [53,526,528, 107,053,056)   3x bf16 padded-NHWC feat1 splits
    //   wt1 [107,053,056, 110,592,000)
    //   wt2 [110,592,000, 114,130,944)
    //   tmp/scores/boxes overlay a3 (dead after conv1)
    __hip_bfloat16* a3p = (__hip_bfloat16*)ws;
    __hip_bfloat16* f1p = (__hip_bfloat16*)(ws + 53526528);
    __hip_bfloat16* wt1 = (__hip_bfloat16*)(ws + 107053056);
    __hip_bfloat16* wt2 = (__hip_bfloat16*)(ws + 110592000);
    float* tmp    = (float*)ws;                     // 17,694,720 B
    float* scores = (float*)(ws + 17694720);        //  3,538,944 B
    float* boxesb = (float*)(ws + 21233664);        // 14,155,776 B (ends 35.4MB)

    prep_misc<<<2072, 256, 0, stream>>>(a3p, f1p, w1, wt1, w2, wt2);
    prep_in<<<2048, 256, 0, stream>>>(p4, a3p);
    conv_mfma<0><<<256, 512, LDS_TOTAL, stream>>>(a3p, wt1, b1, f1p, nullptr);
    conv_mfma<1><<<256, 512, LDS_TOTAL, stream>>>(f1p, wt2, b2, nullptr, feat);
    conv1x1_kernel<<<512, 256, 0, stream>>>(feat, wc, bc, wb, bb, tmp);
    dim3 g2(432, 8);
    boxes_kernel<<<g2, 256, 0, stream>>>(tmp, scores, boxesb);
    topk_props<<<8, 1024, 0, stream>>>(scores, boxesb, props);
}

// Round 20
// 816.990 us; speedup vs baseline: 1.2494x; 1.2494x over previous
//
#include <hip/hip_runtime.h>
#include <hip/hip_bf16.h>
#include <math.h>

// Problem constants
#define NN 8
#define CH 256
#define HH 64
#define WW 64
#define AA 27
#define KK 100
#define MM (HH * WW * AA)   // 110592 per image

typedef __attribute__((ext_vector_type(8))) short short8v;
typedef __attribute__((ext_vector_type(4))) float float4v;

#define SPL 8921088ull    // elems per padded NHWC split plane: 8*66*66*256
#define WSPL 589824ull     // elems per weight split plane: 9*256*256

// LDS partition (bytes): A dbuf 2x25344 + B_h single 73728 = 124416
#define ABUF_B 25344
#define BBUF_B 73728
#define LDS_TOTAL (2 * ABUF_B + BBUF_B)

// ---------------------------------------------------------------------------
// split fp32 -> 3-way bf16 (h + m + l reconstructs to ~2^-24 rel)
// ---------------------------------------------------------------------------
__device__ inline void split3(float x, __hip_bfloat16& h, __hip_bfloat16& m,
                              __hip_bfloat16& l)
{
    h = __float2bfloat16(x);
    float r = x - __bfloat162float(h);
    m = __float2bfloat16(r);
    float r2 = r - __bfloat162float(m);
    l = __float2bfloat16(r2);
}

// ---------------------------------------------------------------------------
// Combined prep: [0,2048) p4 NCHW->padded NHWC x3 splits; [2048,3608) zero
// halo borders; [3608,3864) w1 split; [3864,4120) w2 split. One launch.
// ---------------------------------------------------------------------------
__global__ __launch_bounds__(256)
void prep_all(const float* __restrict__ in, __hip_bfloat16* a3,
              __hip_bfloat16* f1,
              const float* __restrict__ w1, __hip_bfloat16* __restrict__ wt1,
              const float* __restrict__ w2, __hip_bfloat16* __restrict__ wt2)
{
    __shared__ float s_t[64][65];
    const int bid = blockIdx.x;
    const int tid = threadIdx.x;

    if (bid < 2048) {
        // ---- prep_in ----
        const int ct = bid & 3;
        const int row = (bid >> 2) & 63;
        const int n = bid >> 8;
        const int ci0 = ct * 64;

        for (int i = tid; i < 64 * 64; i += 256) {
            int ci = i >> 6, px = i & 63;
            s_t[ci][px] = in[((size_t)(n * 256 + ci0 + ci) << 12) + (row << 6) + px];
        }
        __syncthreads();
        for (int i = tid; i < 64 * 64; i += 256) {
            int px = i >> 6, ci = i & 63;
            __hip_bfloat16 h, m, l;
            split3(s_t[ci][px], h, m, l);
            size_t base = (((size_t)n * 66 + row + 1) * 66 + px + 1) * 256 + ci0 + ci;
            a3[base] = h;
            a3[base + SPL] = m;
            a3[base + 2 * SPL] = l;
        }
    } else if (bid < 3608) {
        // ---- zero halo ----
        int g = (bid - 2048) * 256 + tid;       // exactly 399360
        int arr = g / 66560;
        int rem = g - arr * 66560;
        int n = rem / 8320;
        int rem2 = rem - n * 8320;
        int b = rem2 >> 5;
        int q = rem2 & 31;
        int hp, wp;
        if (b < 66)       { hp = 0;        wp = b; }
        else if (b < 132) { hp = 65;       wp = b - 66; }
        else if (b < 196) { hp = b - 131;  wp = 0; }
        else              { hp = b - 195;  wp = 65; }
        __hip_bfloat16* base = (arr < 3) ? (a3 + (size_t)arr * SPL)
                                         : (f1 + (size_t)(arr - 3) * SPL);
        short8v z = {0, 0, 0, 0, 0, 0, 0, 0};
        *(short8v*)(base + (((size_t)n * 66 + hp) * 66 + wp) * 256 + q * 8) = z;
    } else {
        // ---- weight splits ----
        const bool second = (bid >= 3864);
        const float* w = second ? w2 : w1;
        __hip_bfloat16* wT = second ? wt2 : wt1;
        int t = (bid - (second ? 3864 : 3608)) * 256 + tid;   // 65536
        int co = t >> 8, ci = t & 255;
        const float* src = w + (size_t)t * 9;
#pragma unroll
        for (int tap = 0; tap < 9; ++tap) {
            __hip_bfloat16 h, m, l;
            split3(src[tap], h, m, l);
            size_t base = ((size_t)tap * 256 + co) * 256 + ci;
            wT[base] = h;
            wT[base + WSPL] = m;
            wT[base + 2 * WSPL] = l;
        }
    }
}

// ---------------------------------------------------------------------------
// MFMA 3x3 conv — EXACT r14/r18 kernel (verified absmax 0.125, ~302 us):
// bf16 x3-split, co-tile 128, 512 thr, grid 256, T2 swizzle both-sides,
// A dbuf (global_load_lds) + B_h LDS single buffer restaged per chunk,
// B m/l from global. Accumulation order (chunk, as, tap, bs) per acc.
// r19's B_h-in-registers REGRESSED (VGPR cap 128 -> scratch spill, WRITE
// 63->173MB) — reverted to this verified structure.
// ---------------------------------------------------------------------------
typedef __attribute__((address_space(3))) unsigned lds_u32;
typedef const __attribute__((address_space(1))) unsigned glb_u32;

#define AB_PTR(I_)  ((__hip_bfloat16*)(smem + (I_) * ABUF_B))
#define BB_PTR     ((__hip_bfloat16*)(smem + 2 * ABUF_B))

#define STAGE_A(AS_, CI0_, DST_)  do {                                         \
    const __hip_bfloat16* src_ = a3 + (size_t)(AS_) * SPL +                    \
        ((size_t)(n * 66 + rt * 4) * 66) * 256 + (CI0_);                       \
    __hip_bfloat16* dst_ = (DST_);                                             \
    _Pragma("unroll")                                                          \
    for (int it = 0; it < 4; ++it) {                                           \
        int c = it * 512 + tid;                                                \
        if (c < 1584) {                                                        \
            int ph_ = c >> 3;                                                  \
            int x_ = ph_ & 7;                                                  \
            int p_ = ph_ * 2 + (((c >> 2) ^ (x_ >> 2)) & 1);                   \
            int q_ = (c & 3) ^ (x_ & 3);                                       \
            __builtin_amdgcn_global_load_lds(                                  \
                (glb_u32*)(src_ + (size_t)p_ * 256 + q_ * 8),                  \
                (lds_u32*)(dst_ + c * 8), 16, 0, 0);                           \
        }                                                                      \
    }                                                                          \
} while (0)

#define STAGE_B(CI0_)  do {                                                    \
    __hip_bfloat16* dst_ = BB_PTR;                                             \
    _Pragma("unroll")                                                          \
    for (int it = 0; it < 9; ++it) {                                           \
        int c = it * 512 + tid;                                                \
        {                                                                      \
            int tap_ = c >> 9;                                                 \
            int rem_ = c & 511;                                                \
            int ch_ = rem_ >> 3;                                               \
            int x_ = ch_ & 7;                                                  \
            int co_ = ch_ * 2 + (((rem_ >> 2) ^ (x_ >> 2)) & 1);               \
            int q_ = (rem_ & 3) ^ (x_ & 3);                                    \
            __builtin_amdgcn_global_load_lds(                                  \
                (glb_u32*)(wT + (size_t)tap_ * 65536 +                         \
                           (size_t)(co0 + co_) * 256 + (CI0_) + q_ * 8),       \
                (lds_u32*)(dst_ + c * 8), 16, 0, 0);                           \
        }                                                                      \
    }                                                                          \
} while (0)

#define CONV_COMPUTE(NB_, SB_)  do {                                           \
    const __hip_bfloat16* sb_ = (SB_);                                         \
    const __hip_bfloat16* bbp_ = BB_PTR;                                       \
    _Pragma("unroll")                                                          \
    for (int tap = 0; tap < 9; ++tap) {                                        \
        const int dy_ = tap / 3, dx_ = tap % 3;                                \
        const int pA_ = ((w & 3) + dy_) * 66 + dx_ + l15;                      \
        const int aoff_ = ((((pA_ << 2) | l4) ^ ((pA_ >> 1) & 7)) << 3);       \
        short8v af0 = *(const short8v*)(sb_ + aoff_);                          \
        short8v af1 = *(const short8v*)(sb_ + aoff_ + 512);                    \
        short8v af2 = *(const short8v*)(sb_ + aoff_ + 1024);                   \
        short8v af3 = *(const short8v*)(sb_ + aoff_ + 1536);                   \
        /* bs = 0: B h-split from swizzled LDS [tap][co128][ci32] */           \
        {                                                                      \
            const int coB_ = cohalf * 64 + l15;                                \
            const int boff_ = ((((coB_ << 2) | l4) ^ ((coB_ >> 1) & 7)) << 3); \
            const __hip_bfloat16* bl_ = bbp_ + tap * 4096 + boff_;             \
            short8v b0_ = *(const short8v*)(bl_);                              \
            short8v b1_ = *(const short8v*)(bl_ + 512);                        \
            short8v b2_ = *(const short8v*)(bl_ + 1024);                       \
            short8v b3_ = *(const short8v*)(bl_ + 1536);                       \
            acc[0][0] = __builtin_amdgcn_mfma_f32_16x16x32_bf16(af0, b0_, acc[0][0], 0, 0, 0); \
            acc[1][0] = __builtin_amdgcn_mfma_f32_16x16x32_bf16(af1, b0_, acc[1][0], 0, 0, 0); \
            acc[2][0] = __builtin_amdgcn_mfma_f32_16x16x32_bf16(af2, b0_, acc[2][0], 0, 0, 0); \
            acc[3][0] = __builtin_amdgcn_mfma_f32_16x16x32_bf16(af3, b0_, acc[3][0], 0, 0, 0); \
            acc[0][1] = __builtin_amdgcn_mfma_f32_16x16x32_bf16(af0, b1_, acc[0][1], 0, 0, 0); \
            acc[1][1] = __builtin_amdgcn_mfma_f32_16x16x32_bf16(af1, b1_, acc[1][1], 0, 0, 0); \
            acc[2][1] = __builtin_amdgcn_mfma_f32_16x16x32_bf16(af2, b1_, acc[2][1], 0, 0, 0); \
            acc[3][1] = __builtin_amdgcn_mfma_f32_16x16x32_bf16(af3, b1_, acc[3][1], 0, 0, 0); \
            acc[0][2] = __builtin_amdgcn_mfma_f32_16x16x32_bf16(af0, b2_, acc[0][2], 0, 0, 0); \
            acc[1][2] = __builtin_amdgcn_mfma_f32_16x16x32_bf16(af1, b2_, acc[1][2], 0, 0, 0); \
            acc[2][2] = __builtin_amdgcn_mfma_f32_16x16x32_bf16(af2, b2_, acc[2][2], 0, 0, 0); \
            acc[3][2] = __builtin_amdgcn_mfma_f32_16x16x32_bf16(af3, b2_, acc[3][2], 0, 0, 0); \
            acc[0][3] = __builtin_amdgcn_mfma_f32_16x16x32_bf16(af0, b3_, acc[0][3], 0, 0, 0); \
            acc[1][3] = __builtin_amdgcn_mfma_f32_16x16x32_bf16(af1, b3_, acc[1][3], 0, 0, 0); \
            acc[2][3] = __builtin_amdgcn_mfma_f32_16x16x32_bf16(af2, b3_, acc[2][3], 0, 0, 0); \
            acc[3][3] = __builtin_amdgcn_mfma_f32_16x16x32_bf16(af3, b3_, acc[3][3], 0, 0, 0); \
        }                                                                      \
        /* bs = 1..NB-1: B m/l splits from global */                           \
        const __hip_bfloat16* wp_ = wbase + (size_t)(tap * 65536 + ci0);       \
        _Pragma("unroll")                                                      \
        for (int bs = 1; bs < (NB_); ++bs) {                                   \
            const __hip_bfloat16* wq_ = wp_ + (size_t)bs * WSPL;               \
            short8v b0_ = *(const short8v*)(wq_);                              \
            short8v b1_ = *(const short8v*)(wq_ + 4096);                       \
            short8v b2_ = *(const short8v*)(wq_ + 8192);                       \
            short8v b3_ = *(const short8v*)(wq_ + 12288);                      \
            acc[0][0] = __builtin_amdgcn_mfma_f32_16x16x32_bf16(af0, b0_, acc[0][0], 0, 0, 0); \
            acc[1][0] = __builtin_amdgcn_mfma_f32_16x16x32_bf16(af1, b0_, acc[1][0], 0, 0, 0); \
            acc[2][0] = __builtin_amdgcn_mfma_f32_16x16x32_bf16(af2, b0_, acc[2][0], 0, 0, 0); \
            acc[3][0] = __builtin_amdgcn_mfma_f32_16x16x32_bf16(af3, b0_, acc[3][0], 0, 0, 0); \
            acc[0][1] = __builtin_amdgcn_mfma_f32_16x16x32_bf16(af0, b1_, acc[0][1], 0, 0, 0); \
            acc[1][1] = __builtin_amdgcn_mfma_f32_16x16x32_bf16(af1, b1_, acc[1][1], 0, 0, 0); \
            acc[2][1] = __builtin_amdgcn_mfma_f32_16x16x32_bf16(af2, b1_, acc[2][1], 0, 0, 0); \
            acc[3][1] = __builtin_amdgcn_mfma_f32_16x16x32_bf16(af3, b1_, acc[3][1], 0, 0, 0); \
            acc[0][2] = __builtin_amdgcn_mfma_f32_16x16x32_bf16(af0, b2_, acc[0][2], 0, 0, 0); \
            acc[1][2] = __builtin_amdgcn_mfma_f32_16x16x32_bf16(af1, b2_, acc[1][2], 0, 0, 0); \
            acc[2][2] = __builtin_amdgcn_mfma_f32_16x16x32_bf16(af2, b2_, acc[2][2], 0, 0, 0); \
            acc[3][2] = __builtin_amdgcn_mfma_f32_16x16x32_bf16(af3, b2_, acc[3][2], 0, 0, 0); \
            acc[0][3] = __builtin_amdgcn_mfma_f32_16x16x32_bf16(af0, b3_, acc[0][3], 0, 0, 0); \
            acc[1][3] = __builtin_amdgcn_mfma_f32_16x16x32_bf16(af1, b3_, acc[1][3], 0, 0, 0); \
            acc[2][3] = __builtin_amdgcn_mfma_f32_16x16x32_bf16(af2, b3_, acc[2][3], 0, 0, 0); \
            acc[3][3] = __builtin_amdgcn_mfma_f32_16x16x32_bf16(af3, b3_, acc[3][3], 0, 0, 0); \
        }                                                                      \
    }                                                                          \
} while (0)

template <int MODE>
__global__ __launch_bounds__(512, 1)
void conv_mfma(const __hip_bfloat16* __restrict__ a3,
               const __hip_bfloat16* __restrict__ wT,
               const float* __restrict__ bias,
               __hip_bfloat16* __restrict__ outb,
               float* __restrict__ outf)
{
    extern __shared__ __align__(16) char smem[];

    const int tid = threadIdx.x;
    const int lane = tid & 63, w = tid >> 6;      // (w&3)=row, (w>>2)=cohalf
    const int l15 = lane & 15, l4 = lane >> 4;
    const int cohalf = w >> 2;
    const int bid = blockIdx.x;                   // natural order
    const int cg = bid & 1, rt = (bid >> 1) & 15, n = bid >> 5;
    const int co0 = cg * 128;
    const int row = rt * 4 + (w & 3);             // output row 0..63

    float4v acc[4][4];                            // [pixel-tile p][cout-tile q]
#pragma unroll
    for (int p = 0; p < 4; ++p)
#pragma unroll
        for (int q = 0; q < 4; ++q) acc[p][q] = (float4v){0.f, 0.f, 0.f, 0.f};

    // B (global path): [split][tap][co][ci]
    const __hip_bfloat16* wbase = wT + ((size_t)(co0 + cohalf * 64 + l15)) * 256 + l4 * 8;

    // -------- pipeline: 24 A-phases (chunk, as), B restaged per chunk -----
    STAGE_A(0, 0, AB_PTR(0));
    STAGE_B(0);
    __syncthreads();

    int cur = 0;
    for (int chunk = 0; chunk < 8; ++chunk) {
        const int ci0 = chunk * 32;
        // as = 0 (NB=3): prefetch A(as=1)
        STAGE_A(1, ci0, AB_PTR(cur ^ 1));
        CONV_COMPUTE(3, AB_PTR(cur));
        __syncthreads();
        cur ^= 1;
        // as = 1 (NB=2): prefetch A(as=2)
        STAGE_A(2, ci0, AB_PTR(cur ^ 1));
        CONV_COMPUTE(2, AB_PTR(cur));
        __syncthreads();
        cur ^= 1;
        // as = 2 (NB=1): prefetch A(as=0, next chunk)
        if (chunk < 7) STAGE_A(0, ci0 + 32, AB_PTR(cur ^ 1));
        CONV_COMPUTE(1, AB_PTR(cur));
        __syncthreads();
        if (chunk < 7) {
            STAGE_B(ci0 + 32);        // B_h(next chunk) into the single buffer
            __syncthreads();          // drain before next chunk's reads
        }
        cur ^= 1;
    }

    // epilogue: bias + relu
    float bco[4];
#pragma unroll
    for (int q = 0; q < 4; ++q) bco[q] = bias[co0 + cohalf * 64 + q * 16 + l15];

    if (MODE == 0) {
#pragma unroll
        for (int p = 0; p < 4; ++p)
#pragma unroll
            for (int q = 0; q < 4; ++q) {
#pragma unroll
                for (int v = 0; v < 4; ++v) {
                    float y = fmaxf(acc[p][q][v] + bco[q], 0.f);
                    __hip_bfloat16 h, m, l;
                    split3(y, h, m, l);
                    size_t base = (((size_t)n * 66 + row + 1) * 66 +
                                   p * 16 + l4 * 4 + v + 1) * 256 +
                                  co0 + cohalf * 64 + q * 16 + l15;
                    outb[base] = h;
                    outb[base + SPL] = m;
                    outb[base + 2 * SPL] = l;
                }
            }
    } else {
#pragma unroll
        for (int p = 0; p < 4; ++p)
#pragma unroll
            for (int q = 0; q < 4; ++q) {
                float4v y;
#pragma unroll
                for (int v = 0; v < 4; ++v) y[v] = fmaxf(acc[p][q][v] + bco[q], 0.f);
                *(float4v*)(outf + ((size_t)(n * 256 + co0 + cohalf * 64 + q * 16 + l15) << 12) +
                            row * 64 + p * 16 + l4 * 4) = y;
            }
    }
}

// ---------------------------------------------------------------------------
// FUSED 1x1 convs + anchor/box decode. The 1x1 result (135 ch x 64 px) stays
// in LDS (reusing the staging buffer after a barrier) instead of a global
// tmp round-trip; box decode runs in-block. All fp32 ops identical to the
// previous split kernels (same accumulation loop, same decode expressions)
// -> bitwise-identical scores/boxes.
// ---------------------------------------------------------------------------
__global__ __launch_bounds__(256, 2)
void conv1x1_boxes(const float* __restrict__ feat, const float* __restrict__ wc,
                   const float* __restrict__ bc, const float* __restrict__ wb,
                   const float* __restrict__ bb,
                   float* __restrict__ scores, float* __restrict__ boxes)
{
    __shared__ __align__(16) char shbuf[51456];
    float* s_f = (float*)shbuf;              // [64][64]   (staging)
    float* s_w = (float*)(shbuf + 16384);    // [64][137]  (staging)
    float* s_out = (float*)shbuf;            // [135][64]  (reused after compute)

    const int tid  = threadIdx.x;
    const int n    = blockIdx.x >> 6;
    const int row  = blockIdx.x & 63;        // image row (64 pixels)
    const int px0  = row << 6;
    const int lane = tid & 63;
    const int g    = tid >> 6;

    float acc[34];
#pragma unroll
    for (int k = 0; k < 34; ++k) acc[k] = 0.f;

    for (int chb = 0; chb < 4; ++chb) {
        const int ci0 = chb << 6;
        __syncthreads();
        for (int i = tid; i < 64 * 64; i += 256) {
            int ci = i >> 6, pp = i & 63;
            s_f[ci * 64 + pp] = feat[(((size_t)n * CH + ci0 + ci) << 12) + px0 + pp];
        }
        for (int i = tid; i < 135 * 64; i += 256) {
            int co = i >> 6, ci = i & 63;
            float wv = (co < 27) ? wc[(size_t)co * CH + ci0 + ci]
                                 : wb[(size_t)(co - 27) * CH + ci0 + ci];
            s_w[ci * 137 + co] = wv;
        }
        __syncthreads();
        for (int ci = 0; ci < 64; ++ci) {
            float f = s_f[ci * 64 + lane];
#pragma unroll
            for (int k = 0; k < 34; ++k) {
                int co = g * 34 + k;
                acc[k] += f * s_w[ci * 137 + (co < 135 ? co : 134)];
            }
        }
    }

    // write 1x1 result (+bias) into LDS, replacing the staging buffers
    __syncthreads();
#pragma unroll
    for (int k = 0; k < 34; ++k) {
        int co = g * 34 + k;
        if (co < 135) {
            float b = (co < 27) ? bc[co] : bb[co - 27];
            s_out[co * 64 + lane] = acc[k] + b;
        }
    }
    __syncthreads();

    // decode 27 anchors x 64 pixels
    for (int idx = tid; idx < 27 * 64; idx += 256) {
        const int px = idx & 63;
        const int a = idx >> 6;

        float logit = s_out[a * 64 + px];
        float d0 = s_out[(27 + a * 4 + 0) * 64 + px];
        float d1 = s_out[(27 + a * 4 + 1) * 64 + px];
        float d2 = s_out[(27 + a * 4 + 2) * 64 + px];
        float d3 = s_out[(27 + a * 4 + 3) * 64 + px];

        const int hh = row, ww = px;
        const int si = a / 9, ri = (a / 3) % 3, sci = a % 3;

        double s  = (si == 0) ? 32.0 : (si == 1 ? 64.0 : 128.0);
        double r  = (ri == 0) ? 0.5 : (ri == 1 ? 1.0 : 2.0);
        double sv = (sci == 0) ? 1.0 : (sci == 1 ? pow(2.0, 1.0 / 3.0) : pow(2.0, 2.0 / 3.0));
        double sq = sqrt(r);
        float wa = (float)fmax(s * sv * sq, 1.0);
        float ha = (float)fmax(s * sv / sq, 1.0);
        float bx1 = -0.5f * wa, by1 = -0.5f * ha, bx2 = 0.5f * wa, by2 = 0.5f * ha;

        float sx = ((float)ww + 0.5f) * 4.0f;
        float sy = ((float)hh + 0.5f) * 4.0f;
        float ax1 = fmaxf(bx1 + sx, 0.f);
        float ay1 = fmaxf(by1 + sy, 0.f);
        float ax2 = fminf(fmaxf(bx2 + sx, 0.f), 256.f);
        float ay2 = fminf(fmaxf(by2 + sy, 0.f), 256.f);

        float wdt = ax2 - ax1, hgt = ay2 - ay1;
        float cx = ax1 + 0.5f * wdt, cy = ay1 + 0.5f * hgt;
        float dx = d0 / 10.f, dy = d1 / 10.f, dw = d2 / 5.f, dh = d3 / 5.f;
        float pcx = dx * wdt + cx, pcy = dy * hgt + cy;
        float pw = fmaxf(expf(dw) * wdt, 1.f);
        float ph = fmaxf(expf(dh) * hgt, 1.f);
        float x1 = fminf(fmaxf(pcx - 0.5f * pw, 0.f), 256.f);
        float y1 = fminf(fmaxf(pcy - 0.5f * ph, 0.f), 256.f);
        float x2 = fminf(fmaxf(pcx + 0.5f * pw, 0.f), 256.f);
        float y2 = fminf(fmaxf(pcy + 0.5f * ph, 0.f), 256.f);

        bool inval = ((x2 - x1) < 1.f) || ((y2 - y1) < 1.f);
        float fx1 = inval ? ax1 : x1, fy1 = inval ? ay1 : y1;
        float fx2 = inval ? ax2 : x2, fy2 = inval ? ay2 : y2;
        bool valid = (fx2 > fx1 + 1.f) && (fy2 > fy1 + 1.f);

        const int m = (px0 + px) * 27 + a;
        scores[(size_t)n * MM + m] = valid ? logit : -INFINITY;
        float4 bx = make_float4(fx1, fy1, fx2, fy2);
        *(float4*)&boxes[((size_t)n * MM + m) * 4] = bx;
    }
}

// ---------------------------------------------------------------------------
// Exact per-image top-100 + gather. Bulk scans float4-vectorized (verified).
// ---------------------------------------------------------------------------
__device__ inline unsigned ordf(float f)
{
    unsigned u = __float_as_uint(f);
    return (u & 0x80000000u) ? ~u : (u | 0x80000000u);
}

__global__ void topk_props(const float* __restrict__ scores,
                           const float* __restrict__ boxes,
                           float* __restrict__ props)
{
    const int n = blockIdx.x;
    const int tid = threadIdx.x;
    const float* sc = scores + (size_t)n * MM;

    __shared__ unsigned hist[256];
    __shared__ unsigned u_prefix, u_need, cnt;
    __shared__ unsigned long long selk[100];
    __shared__ unsigned wave_tot[16];

    if (tid == 0) { u_prefix = 0; u_need = 100; cnt = 0; }
    __syncthreads();

    for (int pass = 0; pass < 4; ++pass) {
        if (tid < 256) hist[tid] = 0;
        __syncthreads();
        unsigned pf = u_prefix;
        int shift = 24 - pass * 8;
        for (int i4 = tid; i4 < MM / 4; i4 += 1024) {
            float4 v = ((const float4*)sc)[i4];
#pragma unroll
            for (int k = 0; k < 4; ++k) {
                float f = (k == 0) ? v.x : (k == 1) ? v.y : (k == 2) ? v.z : v.w;
                unsigned o = ordf(f);
                bool match = (pass == 0) || ((o >> (shift + 8)) == (pf >> (shift + 8)));
                if (match) atomicAdd(&hist[(o >> shift) & 255u], 1u);
            }
        }
        __syncthreads();
        if (tid == 0) {
            unsigned nd = u_need;
            int b = 255;
            for (;;) {
                unsigned cb = hist[b];
                if (nd <= cb || b == 0) break;
                nd -= cb;
                --b;
            }
            u_need = nd;
            u_prefix = pf | ((unsigned)b << shift);
        }
        __syncthreads();
    }
    const unsigned T = u_prefix;
    const int need = (int)u_need;
    const int cgt = 100 - need;

    // phase A: collect all keys strictly greater than T (exactly cgt)
    for (int i4 = tid; i4 < MM / 4; i4 += 1024) {
        float4 v = ((const float4*)sc)[i4];
#pragma unroll
        for (int k = 0; k < 4; ++k) {
            float f = (k == 0) ? v.x : (k == 1) ? v.y : (k == 2) ? v.z : v.w;
            unsigned o = ordf(f);
            if (o > T) {
                unsigned pz = atomicAdd(&cnt, 1u);
                selk[pz] = ((unsigned long long)o << 32) |
                           (unsigned long long)(~(unsigned)(i4 * 4 + k));
            }
        }
    }
    __syncthreads();

    // phase B: collect `need` lowest-index entries equal to T, in index order
    unsigned hv = 0;
    for (int base = 0; base < MM; base += 1024) {
        int i = base + tid;
        unsigned o = ordf(sc[i]);
        bool f = (o == T);
        unsigned long long bal = __ballot(f);
        if ((tid & 63) == 0) wave_tot[tid >> 6] = (unsigned)__popcll(bal);
        __syncthreads();
        unsigned wbase = 0, tot = 0;
        int wv = tid >> 6;
        for (int w2 = 0; w2 < 16; ++w2) {
            unsigned cw = wave_tot[w2];
            tot += cw;
            if (w2 < wv) wbase += cw;
        }
        if (f) {
            unsigned rk = hv + wbase +
                          (unsigned)__popcll(bal & ((1ull << (tid & 63)) - 1ull));
            if (rk < (unsigned)need)
                selk[cgt + rk] =
                    ((unsigned long long)o << 32) | (unsigned long long)(~(unsigned)i);
        }
        hv += tot;
        __syncthreads();
        if (hv >= (unsigned)need) break;
    }
    __syncthreads();

    if (tid < 100) {
        unsigned long long k = selk[tid];
        int rank = 0;
        for (int j = 0; j < 100; ++j) rank += (selk[j] > k) ? 1 : 0;
        unsigned idx = ~(unsigned)(k & 0xFFFFFFFFull);
        const float* bx = boxes + ((size_t)n * MM + idx) * 4;
        float x1 = bx[0], y1 = bx[1], x2 = bx[2], y2 = bx[3];
        bool v = (x2 > x1 + 1.f) && (y2 > y1 + 1.f);
        float* o = props + ((size_t)n * 100 + rank) * 5;
        o[0] = v ? (float)n : 0.f;
        o[1] = v ? x1 : 0.f;
        o[2] = v ? y1 : 0.f;
        o[3] = v ? x2 : 0.f;
        o[4] = v ? y2 : 0.f;
    }
}

// ---------------------------------------------------------------------------
extern "C" void kernel_launch(void* const* d_in, const int* in_sizes, int n_in,
                              void* d_out, int out_size, void* d_ws, size_t ws_size,
                              hipStream_t stream)
{
    const float* p4 = (const float*)d_in[0];
    const float* w1 = (const float*)d_in[1];
    const float* b1 = (const float*)d_in[2];
    const float* w2 = (const float*)d_in[3];
    const float* b2 = (const float*)d_in[4];
    const float* wc = (const float*)d_in[5];
    const float* bc = (const float*)d_in[6];
    const float* wb = (const float*)d_in[7];
    const float* bb = (const float*)d_in[8];

    float* out   = (float*)d_out;
    float* props = out;            // [8,100,5]
    float* feat  = out + 4000;     // [8,256,64,64] NCHW fp32

    char* ws = (char*)d_ws;
    // layout (bytes):
    //   a3  [0, 53,526,528)             3x bf16 padded-NHWC input splits
    //   f1  [53,526,528, 107,053,056)   3x bf16 padded-NHWC feat1 splits
    //   wt1 [107,053,056, 110,592,000)
    //   wt2 [110,592,000, 114,130,944)
    //   scores/boxes overlay a3 (dead after conv1)
    __hip_bfloat16* a3p = (__hip_bfloat16*)ws;
    __hip_bfloat16* f1p = (__hip_bfloat16*)(ws + 53526528);
    __hip_bfloat16* wt1 = (__hip_bfloat16*)(ws + 107053056);
    __hip_bfloat16* wt2 = (__hip_bfloat16*)(ws + 110592000);
    float* scores = (float*)(ws + 17694720);        //  3,538,944 B
    float* boxesb = (float*)(ws + 21233664);        // 14,155,776 B (ends 35.4MB)

    prep_all<<<4120, 256, 0, stream>>>(p4, a3p, f1p, w1, wt1, w2, wt2);
    conv_mfma<0><<<256, 512, LDS_TOTAL, stream>>>(a3p, wt1, b1, f1p, nullptr);
    conv_mfma<1><<<256, 512, LDS_TOTAL, stream>>>(f1p, wt2, b2, nullptr, feat);
    conv1x1_boxes<<<512, 256, 0, stream>>>(feat, wc, bc, wb, bb, scores, boxesb);
    topk_props<<<8, 1024, 0, stream>>>(scores, boxesb, props);
}

// Round 21
// 765.054 us; speedup vs baseline: 1.3342x; 1.0679x over previous
//
#include <hip/hip_runtime.h>
#include <hip/hip_bf16.h>
#include <math.h>

// Problem constants
#define NN 8
#define CH 256
#define HH 64
#define WW 64
#define AA 27
#define KK 100
#define MM (HH * WW * AA)   // 110592 per image

typedef __attribute__((ext_vector_type(8))) short short8v;
typedef __attribute__((ext_vector_type(4))) float float4v;

#define SPL 8921088ull    // elems per padded NHWC split plane: 8*66*66*256
#define WSPL 589824ull     // elems per weight split plane: 9*256*256

// LDS partition (bytes): A dbuf 2x25344 + B_h single 73728 = 124416
#define ABUF_B 25344
#define BBUF_B 73728
#define LDS_TOTAL (2 * ABUF_B + BBUF_B)

// ---------------------------------------------------------------------------
// split fp32 -> 3-way bf16 (h + m + l reconstructs to ~2^-24 rel)
// ---------------------------------------------------------------------------
__device__ inline void split3(float x, __hip_bfloat16& h, __hip_bfloat16& m,
                              __hip_bfloat16& l)
{
    h = __float2bfloat16(x);
    float r = x - __bfloat162float(h);
    m = __float2bfloat16(r);
    float r2 = r - __bfloat162float(m);
    l = __float2bfloat16(r2);
}

// ---------------------------------------------------------------------------
// Combined prep: [0,2048) p4 NCHW->padded NHWC x3 splits; [2048,3608) zero
// halo borders; [3608,3864) w1 split; [3864,4120) w2 split. One launch.
// (r20-verified numerics; r18 tail kernels retained separately — the r20
// conv1x1+boxes fusion REGRESSED the tail by dropping decode parallelism.)
// ---------------------------------------------------------------------------
__global__ __launch_bounds__(256)
void prep_all(const float* __restrict__ in, __hip_bfloat16* a3,
              __hip_bfloat16* f1,
              const float* __restrict__ w1, __hip_bfloat16* __restrict__ wt1,
              const float* __restrict__ w2, __hip_bfloat16* __restrict__ wt2)
{
    __shared__ float s_t[64][65];
    const int bid = blockIdx.x;
    const int tid = threadIdx.x;

    if (bid < 2048) {
        // ---- prep_in ----
        const int ct = bid & 3;
        const int row = (bid >> 2) & 63;
        const int n = bid >> 8;
        const int ci0 = ct * 64;

        for (int i = tid; i < 64 * 64; i += 256) {
            int ci = i >> 6, px = i & 63;
            s_t[ci][px] = in[((size_t)(n * 256 + ci0 + ci) << 12) + (row << 6) + px];
        }
        __syncthreads();
        for (int i = tid; i < 64 * 64; i += 256) {
            int px = i >> 6, ci = i & 63;
            __hip_bfloat16 h, m, l;
            split3(s_t[ci][px], h, m, l);
            size_t base = (((size_t)n * 66 + row + 1) * 66 + px + 1) * 256 + ci0 + ci;
            a3[base] = h;
            a3[base + SPL] = m;
            a3[base + 2 * SPL] = l;
        }
    } else if (bid < 3608) {
        // ---- zero halo ----
        int g = (bid - 2048) * 256 + tid;       // exactly 399360
        int arr = g / 66560;
        int rem = g - arr * 66560;
        int n = rem / 8320;
        int rem2 = rem - n * 8320;
        int b = rem2 >> 5;
        int q = rem2 & 31;
        int hp, wp;
        if (b < 66)       { hp = 0;        wp = b; }
        else if (b < 132) { hp = 65;       wp = b - 66; }
        else if (b < 196) { hp = b - 131;  wp = 0; }
        else              { hp = b - 195;  wp = 65; }
        __hip_bfloat16* base = (arr < 3) ? (a3 + (size_t)arr * SPL)
                                         : (f1 + (size_t)(arr - 3) * SPL);
        short8v z = {0, 0, 0, 0, 0, 0, 0, 0};
        *(short8v*)(base + (((size_t)n * 66 + hp) * 66 + wp) * 256 + q * 8) = z;
    } else {
        // ---- weight splits ----
        const bool second = (bid >= 3864);
        const float* w = second ? w2 : w1;
        __hip_bfloat16* wT = second ? wt2 : wt1;
        int t = (bid - (second ? 3864 : 3608)) * 256 + tid;   // 65536
        int co = t >> 8, ci = t & 255;
        const float* src = w + (size_t)t * 9;
#pragma unroll
        for (int tap = 0; tap < 9; ++tap) {
            __hip_bfloat16 h, m, l;
            split3(src[tap], h, m, l);
            size_t base = ((size_t)tap * 256 + co) * 256 + ci;
            wT[base] = h;
            wT[base + WSPL] = m;
            wT[base + 2 * WSPL] = l;
        }
    }
}

// ---------------------------------------------------------------------------
// MFMA 3x3 conv — EXACT r14/r18 kernel (verified absmax 0.125, ~302 us):
// bf16 x3-split, co-tile 128, 512 thr, grid 256, T2 swizzle both-sides,
// A dbuf (global_load_lds) + B_h LDS single buffer restaged per chunk,
// B m/l from global. Accumulation order (chunk, as, tap, bs) per acc.
// Falsified alternatives: merged-phases+setprio (r17, vmcnt FIFO coupling),
// B_h-in-regs (r19, scratch spill), co-tile 256 (r13, neutral).
// ---------------------------------------------------------------------------
typedef __attribute__((address_space(3))) unsigned lds_u32;
typedef const __attribute__((address_space(1))) unsigned glb_u32;

#define AB_PTR(I_)  ((__hip_bfloat16*)(smem + (I_) * ABUF_B))
#define BB_PTR     ((__hip_bfloat16*)(smem + 2 * ABUF_B))

#define STAGE_A(AS_, CI0_, DST_)  do {                                         \
    const __hip_bfloat16* src_ = a3 + (size_t)(AS_) * SPL +                    \
        ((size_t)(n * 66 + rt * 4) * 66) * 256 + (CI0_);                       \
    __hip_bfloat16* dst_ = (DST_);                                             \
    _Pragma("unroll")                                                          \
    for (int it = 0; it < 4; ++it) {                                           \
        int c = it * 512 + tid;                                                \
        if (c < 1584) {                                                        \
            int ph_ = c >> 3;                                                  \
            int x_ = ph_ & 7;                                                  \
            int p_ = ph_ * 2 + (((c >> 2) ^ (x_ >> 2)) & 1);                   \
            int q_ = (c & 3) ^ (x_ & 3);                                       \
            __builtin_amdgcn_global_load_lds(                                  \
                (glb_u32*)(src_ + (size_t)p_ * 256 + q_ * 8),                  \
                (lds_u32*)(dst_ + c * 8), 16, 0, 0);                           \
        }                                                                      \
    }                                                                          \
} while (0)

#define STAGE_B(CI0_)  do {                                                    \
    __hip_bfloat16* dst_ = BB_PTR;                                             \
    _Pragma("unroll")                                                          \
    for (int it = 0; it < 9; ++it) {                                           \
        int c = it * 512 + tid;                                                \
        {                                                                      \
            int tap_ = c >> 9;                                                 \
            int rem_ = c & 511;                                                \
            int ch_ = rem_ >> 3;                                               \
            int x_ = ch_ & 7;                                                  \
            int co_ = ch_ * 2 + (((rem_ >> 2) ^ (x_ >> 2)) & 1);               \
            int q_ = (rem_ & 3) ^ (x_ & 3);                                    \
            __builtin_amdgcn_global_load_lds(                                  \
                (glb_u32*)(wT + (size_t)tap_ * 65536 +                         \
                           (size_t)(co0 + co_) * 256 + (CI0_) + q_ * 8),       \
                (lds_u32*)(dst_ + c * 8), 16, 0, 0);                           \
        }                                                                      \
    }                                                                          \
} while (0)

#define CONV_COMPUTE(NB_, SB_)  do {                                           \
    const __hip_bfloat16* sb_ = (SB_);                                         \
    const __hip_bfloat16* bbp_ = BB_PTR;                                       \
    _Pragma("unroll")                                                          \
    for (int tap = 0; tap < 9; ++tap) {                                        \
        const int dy_ = tap / 3, dx_ = tap % 3;                                \
        const int pA_ = ((w & 3) + dy_) * 66 + dx_ + l15;                      \
        const int aoff_ = ((((pA_ << 2) | l4) ^ ((pA_ >> 1) & 7)) << 3);       \
        short8v af0 = *(const short8v*)(sb_ + aoff_);                          \
        short8v af1 = *(const short8v*)(sb_ + aoff_ + 512);                    \
        short8v af2 = *(const short8v*)(sb_ + aoff_ + 1024);                   \
        short8v af3 = *(const short8v*)(sb_ + aoff_ + 1536);                   \
        /* bs = 0: B h-split from swizzled LDS [tap][co128][ci32] */           \
        {                                                                      \
            const int coB_ = cohalf * 64 + l15;                                \
            const int boff_ = ((((coB_ << 2) | l4) ^ ((coB_ >> 1) & 7)) << 3); \
            const __hip_bfloat16* bl_ = bbp_ + tap * 4096 + boff_;             \
            short8v b0_ = *(const short8v*)(bl_);                              \
            short8v b1_ = *(const short8v*)(bl_ + 512);                        \
            short8v b2_ = *(const short8v*)(bl_ + 1024);                       \
            short8v b3_ = *(const short8v*)(bl_ + 1536);                       \
            acc[0][0] = __builtin_amdgcn_mfma_f32_16x16x32_bf16(af0, b0_, acc[0][0], 0, 0, 0); \
            acc[1][0] = __builtin_amdgcn_mfma_f32_16x16x32_bf16(af1, b0_, acc[1][0], 0, 0, 0); \
            acc[2][0] = __builtin_amdgcn_mfma_f32_16x16x32_bf16(af2, b0_, acc[2][0], 0, 0, 0); \
            acc[3][0] = __builtin_amdgcn_mfma_f32_16x16x32_bf16(af3, b0_, acc[3][0], 0, 0, 0); \
            acc[0][1] = __builtin_amdgcn_mfma_f32_16x16x32_bf16(af0, b1_, acc[0][1], 0, 0, 0); \
            acc[1][1] = __builtin_amdgcn_mfma_f32_16x16x32_bf16(af1, b1_, acc[1][1], 0, 0, 0); \
            acc[2][1] = __builtin_amdgcn_mfma_f32_16x16x32_bf16(af2, b1_, acc[2][1], 0, 0, 0); \
            acc[3][1] = __builtin_amdgcn_mfma_f32_16x16x32_bf16(af3, b1_, acc[3][1], 0, 0, 0); \
            acc[0][2] = __builtin_amdgcn_mfma_f32_16x16x32_bf16(af0, b2_, acc[0][2], 0, 0, 0); \
            acc[1][2] = __builtin_amdgcn_mfma_f32_16x16x32_bf16(af1, b2_, acc[1][2], 0, 0, 0); \
            acc[2][2] = __builtin_amdgcn_mfma_f32_16x16x32_bf16(af2, b2_, acc[2][2], 0, 0, 0); \
            acc[3][2] = __builtin_amdgcn_mfma_f32_16x16x32_bf16(af3, b2_, acc[3][2], 0, 0, 0); \
            acc[0][3] = __builtin_amdgcn_mfma_f32_16x16x32_bf16(af0, b3_, acc[0][3], 0, 0, 0); \
            acc[1][3] = __builtin_amdgcn_mfma_f32_16x16x32_bf16(af1, b3_, acc[1][3], 0, 0, 0); \
            acc[2][3] = __builtin_amdgcn_mfma_f32_16x16x32_bf16(af2, b3_, acc[2][3], 0, 0, 0); \
            acc[3][3] = __builtin_amdgcn_mfma_f32_16x16x32_bf16(af3, b3_, acc[3][3], 0, 0, 0); \
        }                                                                      \
        /* bs = 1..NB-1: B m/l splits from global */                           \
        const __hip_bfloat16* wp_ = wbase + (size_t)(tap * 65536 + ci0);       \
        _Pragma("unroll")                                                      \
        for (int bs = 1; bs < (NB_); ++bs) {                                   \
            const __hip_bfloat16* wq_ = wp_ + (size_t)bs * WSPL;               \
            short8v b0_ = *(const short8v*)(wq_);                              \
            short8v b1_ = *(const short8v*)(wq_ + 4096);                       \
            short8v b2_ = *(const short8v*)(wq_ + 8192);                       \
            short8v b3_ = *(const short8v*)(wq_ + 12288);                      \
            acc[0][0] = __builtin_amdgcn_mfma_f32_16x16x32_bf16(af0, b0_, acc[0][0], 0, 0, 0); \
            acc[1][0] = __builtin_amdgcn_mfma_f32_16x16x32_bf16(af1, b0_, acc[1][0], 0, 0, 0); \
            acc[2][0] = __builtin_amdgcn_mfma_f32_16x16x32_bf16(af2, b0_, acc[2][0], 0, 0, 0); \
            acc[3][0] = __builtin_amdgcn_mfma_f32_16x16x32_bf16(af3, b0_, acc[3][0], 0, 0, 0); \
            acc[0][1] = __builtin_amdgcn_mfma_f32_16x16x32_bf16(af0, b1_, acc[0][1], 0, 0, 0); \
            acc[1][1] = __builtin_amdgcn_mfma_f32_16x16x32_bf16(af1, b1_, acc[1][1], 0, 0, 0); \
            acc[2][1] = __builtin_amdgcn_mfma_f32_16x16x32_bf16(af2, b1_, acc[2][1], 0, 0, 0); \
            acc[3][1] = __builtin_amdgcn_mfma_f32_16x16x32_bf16(af3, b1_, acc[3][1], 0, 0, 0); \
            acc[0][2] = __builtin_amdgcn_mfma_f32_16x16x32_bf16(af0, b2_, acc[0][2], 0, 0, 0); \
            acc[1][2] = __builtin_amdgcn_mfma_f32_16x16x32_bf16(af1, b2_, acc[1][2], 0, 0, 0); \
            acc[2][2] = __builtin_amdgcn_mfma_f32_16x16x32_bf16(af2, b2_, acc[2][2], 0, 0, 0); \
            acc[3][2] = __builtin_amdgcn_mfma_f32_16x16x32_bf16(af3, b2_, acc[3][2], 0, 0, 0); \
            acc[0][3] = __builtin_amdgcn_mfma_f32_16x16x32_bf16(af0, b3_, acc[0][3], 0, 0, 0); \
            acc[1][3] = __builtin_amdgcn_mfma_f32_16x16x32_bf16(af1, b3_, acc[1][3], 0, 0, 0); \
            acc[2][3] = __builtin_amdgcn_mfma_f32_16x16x32_bf16(af2, b3_, acc[2][3], 0, 0, 0); \
            acc[3][3] = __builtin_amdgcn_mfma_f32_16x16x32_bf16(af3, b3_, acc[3][3], 0, 0, 0); \
        }                                                                      \
    }                                                                          \
} while (0)

template <int MODE>
__global__ __launch_bounds__(512, 1)
void conv_mfma(const __hip_bfloat16* __restrict__ a3,
               const __hip_bfloat16* __restrict__ wT,
               const float* __restrict__ bias,
               __hip_bfloat16* __restrict__ outb,
               float* __restrict__ outf)
{
    extern __shared__ __align__(16) char smem[];

    const int tid = threadIdx.x;
    const int lane = tid & 63, w = tid >> 6;      // (w&3)=row, (w>>2)=cohalf
    const int l15 = lane & 15, l4 = lane >> 4;
    const int cohalf = w >> 2;
    const int bid = blockIdx.x;                   // natural order
    const int cg = bid & 1, rt = (bid >> 1) & 15, n = bid >> 5;
    const int co0 = cg * 128;
    const int row = rt * 4 + (w & 3);             // output row 0..63

    float4v acc[4][4];                            // [pixel-tile p][cout-tile q]
#pragma unroll
    for (int p = 0; p < 4; ++p)
#pragma unroll
        for (int q = 0; q < 4; ++q) acc[p][q] = (float4v){0.f, 0.f, 0.f, 0.f};

    // B (global path): [split][tap][co][ci]
    const __hip_bfloat16* wbase = wT + ((size_t)(co0 + cohalf * 64 + l15)) * 256 + l4 * 8;

    // -------- pipeline: 24 A-phases (chunk, as), B restaged per chunk -----
    STAGE_A(0, 0, AB_PTR(0));
    STAGE_B(0);
    __syncthreads();

    int cur = 0;
    for (int chunk = 0; chunk < 8; ++chunk) {
        const int ci0 = chunk * 32;
        // as = 0 (NB=3): prefetch A(as=1)
        STAGE_A(1, ci0, AB_PTR(cur ^ 1));
        CONV_COMPUTE(3, AB_PTR(cur));
        __syncthreads();
        cur ^= 1;
        // as = 1 (NB=2): prefetch A(as=2)
        STAGE_A(2, ci0, AB_PTR(cur ^ 1));
        CONV_COMPUTE(2, AB_PTR(cur));
        __syncthreads();
        cur ^= 1;
        // as = 2 (NB=1): prefetch A(as=0, next chunk)
        if (chunk < 7) STAGE_A(0, ci0 + 32, AB_PTR(cur ^ 1));
        CONV_COMPUTE(1, AB_PTR(cur));
        __syncthreads();
        if (chunk < 7) {
            STAGE_B(ci0 + 32);        // B_h(next chunk) into the single buffer
            __syncthreads();          // drain before next chunk's reads
        }
        cur ^= 1;
    }

    // epilogue: bias + relu
    float bco[4];
#pragma unroll
    for (int q = 0; q < 4; ++q) bco[q] = bias[co0 + cohalf * 64 + q * 16 + l15];

    if (MODE == 0) {
#pragma unroll
        for (int p = 0; p < 4; ++p)
#pragma unroll
            for (int q = 0; q < 4; ++q) {
#pragma unroll
                for (int v = 0; v < 4; ++v) {
                    float y = fmaxf(acc[p][q][v] + bco[q], 0.f);
                    __hip_bfloat16 h, m, l;
                    split3(y, h, m, l);
                    size_t base = (((size_t)n * 66 + row + 1) * 66 +
                                   p * 16 + l4 * 4 + v + 1) * 256 +
                                  co0 + cohalf * 64 + q * 16 + l15;
                    outb[base] = h;
                    outb[base + SPL] = m;
                    outb[base + 2 * SPL] = l;
                }
            }
    } else {
#pragma unroll
        for (int p = 0; p < 4; ++p)
#pragma unroll
            for (int q = 0; q < 4; ++q) {
                float4v y;
#pragma unroll
                for (int v = 0; v < 4; ++v) y[v] = fmaxf(acc[p][q][v] + bco[q], 0.f);
                *(float4v*)(outf + ((size_t)(n * 256 + co0 + cohalf * 64 + q * 16 + l15) << 12) +
                            row * 64 + p * 16 + l4 * 4) = y;
            }
    }
}

// ---------------------------------------------------------------------------
// Fused 1x1 convs: 135 output channels (27 logits + 108 deltas). fp32.
// (r18-verified; separate from box decode — r20's fusion regressed.)
// ---------------------------------------------------------------------------
__global__ __launch_bounds__(256, 2)
void conv1x1_kernel(const float* __restrict__ feat, const float* __restrict__ wc,
                    const float* __restrict__ bc, const float* __restrict__ wb,
                    const float* __restrict__ bb, float* __restrict__ tmp)
{
    __shared__ float s_f[64][64];
    __shared__ float s_w[64][137];

    const int tid  = threadIdx.x;
    const int n    = blockIdx.x >> 6;
    const int px0  = (blockIdx.x & 63) << 6;
    const int lane = tid & 63;
    const int g    = tid >> 6;

    float acc[34];
#pragma unroll
    for (int k = 0; k < 34; ++k) acc[k] = 0.f;

    for (int chb = 0; chb < 4; ++chb) {
        const int ci0 = chb << 6;
        __syncthreads();
        for (int i = tid; i < 64 * 64; i += 256) {
            int ci = i >> 6, pp = i & 63;
            s_f[ci][pp] = feat[(((size_t)n * CH + ci0 + ci) << 12) + px0 + pp];
        }
        for (int i = tid; i < 135 * 64; i += 256) {
            int co = i >> 6, ci = i & 63;
            float wv = (co < 27) ? wc[(size_t)co * CH + ci0 + ci]
                                 : wb[(size_t)(co - 27) * CH + ci0 + ci];
            s_w[ci][co] = wv;
        }
        __syncthreads();
        for (int ci = 0; ci < 64; ++ci) {
            float f = s_f[ci][lane];
#pragma unroll
            for (int k = 0; k < 34; ++k) {
                int co = g * 34 + k;
                acc[k] += f * s_w[ci][co < 135 ? co : 134];
            }
        }
    }
#pragma unroll
    for (int k = 0; k < 34; ++k) {
        int co = g * 34 + k;
        if (co < 135) {
            float b = (co < 27) ? bc[co] : bb[co - 27];
            tmp[((size_t)n * 135 + co) * 4096 + px0 + lane] = acc[k] + b;
        }
    }
}

// ---------------------------------------------------------------------------
// Anchors + apply_deltas + validity + score masking. (r18-verified,
// high-parallelism: 3456 blocks x 256 thr, 1 anchor-pixel per thread.)
// ---------------------------------------------------------------------------
__global__ void boxes_kernel(const float* __restrict__ tmp,
                             float* __restrict__ scores, float* __restrict__ boxes)
{
    const int n = blockIdx.y;
    const int i = blockIdx.x * 256 + threadIdx.x;
    const int a = i >> 12;
    const int p = i & 4095;

    const float* t = tmp + (size_t)n * 135 * 4096;
    float logit = t[(size_t)a * 4096 + p];
    float d0 = t[((size_t)(27 + a * 4 + 0)) * 4096 + p];
    float d1 = t[((size_t)(27 + a * 4 + 1)) * 4096 + p];
    float d2 = t[((size_t)(27 + a * 4 + 2)) * 4096 + p];
    float d3 = t[((size_t)(27 + a * 4 + 3)) * 4096 + p];

    const int hh = p >> 6, ww = p & 63;
    const int si = a / 9, ri = (a / 3) % 3, sci = a % 3;

    double s  = (si == 0) ? 32.0 : (si == 1 ? 64.0 : 128.0);
    double r  = (ri == 0) ? 0.5 : (ri == 1 ? 1.0 : 2.0);
    double sv = (sci == 0) ? 1.0 : (sci == 1 ? pow(2.0, 1.0 / 3.0) : pow(2.0, 2.0 / 3.0));
    double sq = sqrt(r);
    float wa = (float)fmax(s * sv * sq, 1.0);
    float ha = (float)fmax(s * sv / sq, 1.0);
    float bx1 = -0.5f * wa, by1 = -0.5f * ha, bx2 = 0.5f * wa, by2 = 0.5f * ha;

    float sx = ((float)ww + 0.5f) * 4.0f;
    float sy = ((float)hh + 0.5f) * 4.0f;
    float ax1 = fmaxf(bx1 + sx, 0.f);
    float ay1 = fmaxf(by1 + sy, 0.f);
    float ax2 = fminf(fmaxf(bx2 + sx, 0.f), 256.f);
    float ay2 = fminf(fmaxf(by2 + sy, 0.f), 256.f);

    float wdt = ax2 - ax1, hgt = ay2 - ay1;
    float cx = ax1 + 0.5f * wdt, cy = ay1 + 0.5f * hgt;
    float dx = d0 / 10.f, dy = d1 / 10.f, dw = d2 / 5.f, dh = d3 / 5.f;
    float pcx = dx * wdt + cx, pcy = dy * hgt + cy;
    float pw = fmaxf(expf(dw) * wdt, 1.f);
    float ph = fmaxf(expf(dh) * hgt, 1.f);
    float x1 = fminf(fmaxf(pcx - 0.5f * pw, 0.f), 256.f);
    float y1 = fminf(fmaxf(pcy - 0.5f * ph, 0.f), 256.f);
    float x2 = fminf(fmaxf(pcx + 0.5f * pw, 0.f), 256.f);
    float y2 = fminf(fmaxf(pcy + 0.5f * ph, 0.f), 256.f);

    bool inval = ((x2 - x1) < 1.f) || ((y2 - y1) < 1.f);
    float fx1 = inval ? ax1 : x1, fy1 = inval ? ay1 : y1;
    float fx2 = inval ? ax2 : x2, fy2 = inval ? ay2 : y2;
    bool valid = (fx2 > fx1 + 1.f) && (fy2 > fy1 + 1.f);

    const int m = p * 27 + a;
    scores[(size_t)n * MM + m] = valid ? logit : -INFINITY;
    float4 bx = make_float4(fx1, fy1, fx2, fy2);
    *(float4*)&boxes[((size_t)n * MM + m) * 4] = bx;
}

// ---------------------------------------------------------------------------
// Exact per-image top-100 + gather. Bulk scans float4-vectorized (verified).
// ---------------------------------------------------------------------------
__device__ inline unsigned ordf(float f)
{
    unsigned u = __float_as_uint(f);
    return (u & 0x80000000u) ? ~u : (u | 0x80000000u);
}

__global__ void topk_props(const float* __restrict__ scores,
                           const float* __restrict__ boxes,
                           float* __restrict__ props)
{
    const int n = blockIdx.x;
    const int tid = threadIdx.x;
    const float* sc = scores + (size_t)n * MM;

    __shared__ unsigned hist[256];
    __shared__ unsigned u_prefix, u_need, cnt;
    __shared__ unsigned long long selk[100];
    __shared__ unsigned wave_tot[16];

    if (tid == 0) { u_prefix = 0; u_need = 100; cnt = 0; }
    __syncthreads();

    for (int pass = 0; pass < 4; ++pass) {
        if (tid < 256) hist[tid] = 0;
        __syncthreads();
        unsigned pf = u_prefix;
        int shift = 24 - pass * 8;
        for (int i4 = tid; i4 < MM / 4; i4 += 1024) {
            float4 v = ((const float4*)sc)[i4];
#pragma unroll
            for (int k = 0; k < 4; ++k) {
                float f = (k == 0) ? v.x : (k == 1) ? v.y : (k == 2) ? v.z : v.w;
                unsigned o = ordf(f);
                bool match = (pass == 0) || ((o >> (shift + 8)) == (pf >> (shift + 8)));
                if (match) atomicAdd(&hist[(o >> shift) & 255u], 1u);
            }
        }
        __syncthreads();
        if (tid == 0) {
            unsigned nd = u_need;
            int b = 255;
            for (;;) {
                unsigned cb = hist[b];
                if (nd <= cb || b == 0) break;
                nd -= cb;
                --b;
            }
            u_need = nd;
            u_prefix = pf | ((unsigned)b << shift);
        }
        __syncthreads();
    }
    const unsigned T = u_prefix;
    const int need = (int)u_need;
    const int cgt = 100 - need;

    // phase A: collect all keys strictly greater than T (exactly cgt)
    for (int i4 = tid; i4 < MM / 4; i4 += 1024) {
        float4 v = ((const float4*)sc)[i4];
#pragma unroll
        for (int k = 0; k < 4; ++k) {
            float f = (k == 0) ? v.x : (k == 1) ? v.y : (k == 2) ? v.z : v.w;
            unsigned o = ordf(f);
            if (o > T) {
                unsigned pz = atomicAdd(&cnt, 1u);
                selk[pz] = ((unsigned long long)o << 32) |
                           (unsigned long long)(~(unsigned)(i4 * 4 + k));
            }
        }
    }
    __syncthreads();

    // phase B: collect `need` lowest-index entries equal to T, in index order
    unsigned hv = 0;
    for (int base = 0; base < MM; base += 1024) {
        int i = base + tid;
        unsigned o = ordf(sc[i]);
        bool f = (o == T);
        unsigned long long bal = __ballot(f);
        if ((tid & 63) == 0) wave_tot[tid >> 6] = (unsigned)__popcll(bal);
        __syncthreads();
        unsigned wbase = 0, tot = 0;
        int wv = tid >> 6;
        for (int w2 = 0; w2 < 16; ++w2) {
            unsigned cw = wave_tot[w2];
            tot += cw;
            if (w2 < wv) wbase += cw;
        }
        if (f) {
            unsigned rk = hv + wbase +
                          (unsigned)__popcll(bal & ((1ull << (tid & 63)) - 1ull));
            if (rk < (unsigned)need)
                selk[cgt + rk] =
                    ((unsigned long long)o << 32) | (unsigned long long)(~(unsigned)i);
        }
        hv += tot;
        __syncthreads();
        if (hv >= (unsigned)need) break;
    }
    __syncthreads();

    if (tid < 100) {
        unsigned long long k = selk[tid];
        int rank = 0;
        for (int j = 0; j < 100; ++j) rank += (selk[j] > k) ? 1 : 0;
        unsigned idx = ~(unsigned)(k & 0xFFFFFFFFull);
        const float* bx = boxes + ((size_t)n * MM + idx) * 4;
        float x1 = bx[0], y1 = bx[1], x2 = bx[2], y2 = bx[3];
        bool v = (x2 > x1 + 1.f) && (y2 > y1 + 1.f);
        float* o = props + ((size_t)n * 100 + rank) * 5;
        o[0] = v ? (float)n : 0.f;
        o[1] = v ? x1 : 0.f;
        o[2] = v ? y1 : 0.f;
        o[3] = v ? x2 : 0.f;
        o[4] = v ? y2 : 0.f;
    }
}

// ---------------------------------------------------------------------------
extern "C" void kernel_launch(void* const* d_in, const int* in_sizes, int n_in,
                              void* d_out, int out_size, void* d_ws, size_t ws_size,
                              hipStream_t stream)
{
    const float* p4 = (const float*)d_in[0];
    const float* w1 = (const float*)d_in[1];
    const float* b1 = (const float*)d_in[2];
    const float* w2 = (const float*)d_in[3];
    const float* b2 = (const float*)d_in[4];
    const float* wc = (const float*)d_in[5];
    const float* bc = (const float*)d_in[6];
    const float* wb = (const float*)d_in[7];
    const float* bb = (const float*)d_in[8];

    float* out   = (float*)d_out;
    float* props = out;            // [8,100,5]
    float* feat  = out + 4000;     // [8,256,64,64] NCHW fp32

    char* ws = (char*)d_ws;
    // layout (bytes):
    //   a3  [0, 53,526,528)             3x bf16 padded-NHWC input splits
    //   f1  [53,526,528, 107,053,056)   3x bf16 padded-NHWC feat1 splits
    //   wt1 [107,053,056, 110,592,000)
    //   wt2 [110,592,000, 114,130,944)
    //   tmp/scores/boxes overlay a3 (dead after conv1)
    __hip_bfloat16* a3p = (__hip_bfloat16*)ws;
    __hip_bfloat16* f1p = (__hip_bfloat16*)(ws + 53526528);
    __hip_bfloat16* wt1 = (__hip_bfloat16*)(ws + 107053056);
    __hip_bfloat16* wt2 = (__hip_bfloat16*)(ws + 110592000);
    float* tmp    = (float*)ws;                     // 17,694,720 B
    float* scores = (float*)(ws + 17694720);        //  3,538,944 B
    float* boxesb = (float*)(ws + 21233664);        // 14,155,776 B (ends 35.4MB)

    prep_all<<<4120, 256, 0, stream>>>(p4, a3p, f1p, w1, wt1, w2, wt2);
    conv_mfma<0><<<256, 512, LDS_TOTAL, stream>>>(a3p, wt1, b1, f1p, nullptr);
    conv_mfma<1><<<256, 512, LDS_TOTAL, stream>>>(f1p, wt2, b2, nullptr, feat);
    conv1x1_kernel<<<512, 256, 0, stream>>>(feat, wc, bc, wb, bb, tmp);
    dim3 g2(432, 8);
    boxes_kernel<<<g2, 256, 0, stream>>>(tmp, scores, boxesb);
    topk_props<<<8, 1024, 0, stream>>>(scores, boxesb, props);
}